// Round 1
// baseline (76.443 us; speedup 1.0000x reference)
//
#include <hip/hip_runtime.h>
#include <math.h>

#define QN 8192
#define AN 2048
#define DN 64
#define ASTRIDE 40
#define NFIELDS 17

#define SQ2f      1.4142135623730951f
#define INV_SQ2f  0.7071067811865476f
#define SQ6_INVf  0.4082482904638631f
#define SQ2_3f    0.816496580927726f

__device__ __forceinline__ float wave_sum(float v) {
#pragma unroll
  for (int off = 32; off > 0; off >>= 1) v += __shfl_xor(v, off, 64);
  return v;
}

// ---------------- Kernel A: per-atom precompute ----------------
// out[a][0..39]:
//  0-2 coords, 3 alpha, 4 c0e, 5 c0o, 6-8 dip(+b), 9-11 biv(+b),
//  12-17 quad sym [xx,xy,xz,yy,yz,zz], 18-23 odd quad sym,
//  24-26 a1o, 27-29 a1e, 30-34 a2e, 35-39 a2o
__global__ __launch_bounds__(256) void precompute_atoms(
    const float* __restrict__ atom_coords, const float* __restrict__ alpha,
    const float* __restrict__ even_scalar, const float* __restrict__ odd_scalar,
    const float* __restrict__ odd_vector, const float* __restrict__ even_vector,
    const float* __restrict__ even_tensor, const float* __restrict__ odd_tensor,
    const float* __restrict__ W, const float* __restrict__ b,
    float* __restrict__ out)
{
  const int a = blockIdx.x * 4 + (threadIdx.x >> 6);
  const int d = threadIdx.x & 63;

  const float es  = even_scalar[a * DN + d];
  const float os  = odd_scalar[a * DN + d];
  const float ov0 = odd_vector[(a * DN + d) * 3 + 0];
  const float ov1 = odd_vector[(a * DN + d) * 3 + 1];
  const float ov2 = odd_vector[(a * DN + d) * 3 + 2];
  const float ev0 = even_vector[(a * DN + d) * 3 + 0];
  const float ev1 = even_vector[(a * DN + d) * 3 + 1];
  const float ev2 = even_vector[(a * DN + d) * 3 + 2];
  const float et0 = even_tensor[(a * DN + d) * 5 + 0];
  const float et1 = even_tensor[(a * DN + d) * 5 + 1];
  const float et2 = even_tensor[(a * DN + d) * 5 + 2];
  const float et3 = even_tensor[(a * DN + d) * 5 + 3];
  const float et4 = even_tensor[(a * DN + d) * 5 + 4];
  const float ot0 = odd_tensor[(a * DN + d) * 5 + 0];
  const float ot1 = odd_tensor[(a * DN + d) * 5 + 1];
  const float ot2 = odd_tensor[(a * DN + d) * 5 + 2];
  const float ot3 = odd_tensor[(a * DN + d) * 5 + 3];
  const float ot4 = odd_tensor[(a * DN + d) * 5 + 4];

  const float w0 = W[0 * DN + d];
  const float w1 = W[1 * DN + d];
  const float w2 = W[2 * DN + d];
  const float w3 = W[3 * DN + d];
  const float w4 = W[4 * DN + d];
  const float w5 = W[5 * DN + d];
  const float w6 = W[6 * DN + d];
  const float w7 = W[7 * DN + d];
  const float w8 = W[8 * DN + d];
  const float w9 = W[9 * DN + d];

  float r[34];
  r[0]  = es * w0;
  r[1]  = os * w1;
  r[2]  = ov0 * w2; r[3]  = ov1 * w2; r[4]  = ov2 * w2;
  r[5]  = ev0 * w3; r[6]  = ev1 * w3; r[7]  = ev2 * w3;
  r[8]  = et0 * w4; r[9]  = et1 * w4; r[10] = et2 * w4; r[11] = et3 * w4; r[12] = et4 * w4;
  r[13] = ot0 * w5; r[14] = ot1 * w5; r[15] = ot2 * w5; r[16] = ot3 * w5; r[17] = ot4 * w5;
  r[18] = ov0 * w6; r[19] = ov1 * w6; r[20] = ov2 * w6;
  r[21] = ev0 * w7; r[22] = ev1 * w7; r[23] = ev2 * w7;
  r[24] = et0 * w8; r[25] = et1 * w8; r[26] = et2 * w8; r[27] = et3 * w8; r[28] = et4 * w8;
  r[29] = ot0 * w9; r[30] = ot1 * w9; r[31] = ot2 * w9; r[32] = ot3 * w9; r[33] = ot4 * w9;

#pragma unroll
  for (int k = 0; k < 34; ++k) r[k] = wave_sum(r[k]);

  if (d == 0) {
    float* o = out + (size_t)a * ASTRIDE;
    o[0] = atom_coords[a * 3 + 0];
    o[1] = atom_coords[a * 3 + 1];
    o[2] = atom_coords[a * 3 + 2];
    o[3] = alpha[a];
    o[4] = r[0] + b[0];
    o[5] = r[1] + b[1];
    o[6] = r[2] + b[2]; o[7] = r[3] + b[2]; o[8] = r[4] + b[2];
    o[9] = r[5] + b[3]; o[10] = r[6] + b[3]; o[11] = r[7] + b[3];
    // even quadrupole from coeffs (+b[4] each)
    {
      float c0 = r[8] + b[4], c1 = r[9] + b[4], c2 = r[10] + b[4],
            c3 = r[11] + b[4], c4 = r[12] + b[4];
      float zz = c1 * SQ2_3f;
      float xx = 0.5f * (c0 * SQ2f - zz);
      float yy = 0.5f * (-c0 * SQ2f - zz);
      float xy = c2 * INV_SQ2f, xz = c3 * INV_SQ2f, yz = c4 * INV_SQ2f;
      o[12] = xx; o[13] = xy; o[14] = xz; o[15] = yy; o[16] = yz; o[17] = zz;
    }
    // odd quadrupole (+b[5])
    {
      float c0 = r[13] + b[5], c1 = r[14] + b[5], c2 = r[15] + b[5],
            c3 = r[16] + b[5], c4 = r[17] + b[5];
      float zz = c1 * SQ2_3f;
      float xx = 0.5f * (c0 * SQ2f - zz);
      float yy = 0.5f * (-c0 * SQ2f - zz);
      float xy = c2 * INV_SQ2f, xz = c3 * INV_SQ2f, yz = c4 * INV_SQ2f;
      o[18] = xx; o[19] = xy; o[20] = xz; o[21] = yy; o[22] = yz; o[23] = zz;
    }
    o[24] = r[18]; o[25] = r[19]; o[26] = r[20];
    o[27] = r[21]; o[28] = r[22]; o[29] = r[23];
    o[30] = r[24]; o[31] = r[25]; o[32] = r[26]; o[33] = r[27]; o[34] = r[28];
    o[35] = r[29]; o[36] = r[30]; o[37] = r[31]; o[38] = r[32]; o[39] = r[33];
  }
}

// ---------------- Kernel B: pair loop, per-(query, atom-split) partials ----------------
// P layout: P[(s*NFIELDS + f)*QN + q]
__global__ __launch_bounds__(256) void splat_partial(
    const float* __restrict__ qcoord, const float* __restrict__ ad,
    const float* __restrict__ b, float* __restrict__ P, int chunk)
{
  const int q = blockIdx.x * 256 + threadIdx.x;
  const int s = blockIdx.y;

  const float qx = qcoord[q * 3 + 0];
  const float qy = qcoord[q * 3 + 1];
  const float qz = qcoord[q * 3 + 2];
  const float b_ea = b[6] + b[8];
  const float b_oa = b[7] + b[9];

  float Sw = 0.f, Sc0e = 0.f, Sc0o = 0.f;
  float Sdx = 0.f, Sdy = 0.f, Sdz = 0.f;
  float Sqx = 0.f, Sqy = 0.f, Sqz = 0.f;
  float Sbx = 0.f, Sby = 0.f, Sbz = 0.f;
  float Sox = 0.f, Soy = 0.f, Soz = 0.f;
  float Sea = 0.f, Soa = 0.f;

  const int a0 = s * chunk;
  for (int i = 0; i < chunk; ++i) {
    const float* p = ad + (size_t)(a0 + i) * ASTRIDE;
    const float ax = p[0], ay = p[1], az = p[2], al = p[3];
    const float dx = qx - ax, dy = qy - ay, dz = qz - az;
    const float d2 = fmaf(dx, dx, fmaf(dy, dy, dz * dz));
    const float w = __expf(-al * d2);
    const float inv = (d2 > 1e-12f) ? __frsqrt_rn(d2) : 0.0f;
    const float ux = dx * inv, uy = dy * inv, uz = dz * inv;
    const float xx = ux * ux, yy = uy * uy, zz = uz * uz;
    const float y0 = (xx - yy) * INV_SQ2f;
    const float y1 = (2.0f * zz - xx - yy) * SQ6_INVf;
    const float y2 = SQ2f * ux * uy;
    const float y3 = SQ2f * ux * uz;
    const float y4 = SQ2f * uy * uz;

    Sw += w;
    Sc0e = fmaf(w, p[4], Sc0e);
    Sc0o = fmaf(w, p[5], Sc0o);
    Sdx = fmaf(w, p[6], Sdx); Sdy = fmaf(w, p[7], Sdy); Sdz = fmaf(w, p[8], Sdz);
    Sbx = fmaf(w, p[9], Sbx); Sby = fmaf(w, p[10], Sby); Sbz = fmaf(w, p[11], Sbz);

    const float wux = w * ux, wuy = w * uy, wuz = w * uz;
    Sqx = fmaf(p[12], wux, fmaf(p[13], wuy, fmaf(p[14], wuz, Sqx)));
    Sqy = fmaf(p[13], wux, fmaf(p[15], wuy, fmaf(p[16], wuz, Sqy)));
    Sqz = fmaf(p[14], wux, fmaf(p[16], wuy, fmaf(p[17], wuz, Sqz)));
    Sox = fmaf(p[18], wux, fmaf(p[19], wuy, fmaf(p[20], wuz, Sox)));
    Soy = fmaf(p[19], wux, fmaf(p[21], wuy, fmaf(p[22], wuz, Soy)));
    Soz = fmaf(p[20], wux, fmaf(p[22], wuy, fmaf(p[23], wuz, Soz)));

    const float e_ang = fmaf(ux, p[24], fmaf(uy, p[25], fmaf(uz, p[26],
                       fmaf(y0, p[30], fmaf(y1, p[31], fmaf(y2, p[32],
                       fmaf(y3, p[33], fmaf(y4, p[34], b_ea))))))));
    const float o_ang = fmaf(ux, p[27], fmaf(uy, p[28], fmaf(uz, p[29],
                       fmaf(y0, p[35], fmaf(y1, p[36], fmaf(y2, p[37],
                       fmaf(y3, p[38], fmaf(y4, p[39], b_oa))))))));
    Sea = fmaf(w, e_ang, Sea);
    Soa = fmaf(w, o_ang, Soa);
  }

  float* Pb = P + (size_t)s * NFIELDS * QN + q;
  Pb[0 * QN]  = Sw;
  Pb[1 * QN]  = Sc0e;
  Pb[2 * QN]  = Sc0o;
  Pb[3 * QN]  = Sdx;  Pb[4 * QN]  = Sdy;  Pb[5 * QN]  = Sdz;
  Pb[6 * QN]  = Sqx;  Pb[7 * QN]  = Sqy;  Pb[8 * QN]  = Sqz;
  Pb[9 * QN]  = Sbx;  Pb[10 * QN] = Sby;  Pb[11 * QN] = Sbz;
  Pb[12 * QN] = Sox;  Pb[13 * QN] = Soy;  Pb[14 * QN] = Soz;
  Pb[15 * QN] = Sea;
  Pb[16 * QN] = Soa;
}

// ---------------- Kernel C: reduce partials + finalize outputs ----------------
__global__ __launch_bounds__(256) void finalize(
    const float* __restrict__ P, float* __restrict__ out, int nsplit)
{
  const int q = blockIdx.x * 256 + threadIdx.x;
  float acc[NFIELDS];
#pragma unroll
  for (int f = 0; f < NFIELDS; ++f) acc[f] = 0.f;
  for (int s = 0; s < nsplit; ++s) {
#pragma unroll
    for (int f = 0; f < NFIELDS; ++f)
      acc[f] += P[((size_t)s * NFIELDS + f) * QN + q];
  }

  const float Sw = fmaxf(acc[0], 1e-8f);
  const float inv = 1.0f / Sw;
  const float scal = acc[1] * inv;
  const float pse  = acc[2] * inv;
  const float vx = (acc[3] + acc[6]) * inv;
  const float vy = (acc[4] + acc[7]) * inv;
  const float vz = (acc[5] + acc[8]) * inv;
  const float bx = (acc[9] + acc[12]) * inv;
  const float by = (acc[10] + acc[13]) * inv;
  const float bz = (acc[11] + acc[14]) * inv;
  const float ea = acc[15] * inv;
  const float oa = acc[16] * inv;

  const float evenc = scal + ea;
  const float oddc  = pse + oa;
  const float vn = sqrtf(fmaf(vx, vx, fmaf(vy, vy, vz * vz)));
  const float bn = sqrtf(fmaf(bx, bx, fmaf(by, by, bz * bz)));
  const float total = evenc + oddc + 0.1f * vn + 0.05f * bn;

  out[q] = total;
  out[QN + q] = evenc;
  out[2 * QN + q] = oddc;
  float* mv = out + 3 * QN + (size_t)q * 16;
  mv[0] = scal;
  mv[1] = vx; mv[2] = vy; mv[3] = vz;
  mv[4] = 0.f;
  mv[5] = bz; mv[6] = -by; mv[7] = bx;
  mv[8] = 0.f; mv[9] = 0.f; mv[10] = 0.f;
  mv[11] = pse;
  mv[12] = 0.f; mv[13] = 0.f; mv[14] = 0.f; mv[15] = 0.f;
}

extern "C" void kernel_launch(void* const* d_in, const int* in_sizes, int n_in,
                              void* d_out, int out_size, void* d_ws, size_t ws_size,
                              hipStream_t stream) {
  const float* query_coords = (const float*)d_in[0];
  const float* atom_coords  = (const float*)d_in[1];
  const float* alpha        = (const float*)d_in[2];
  const float* even_scalar  = (const float*)d_in[3];
  const float* odd_scalar   = (const float*)d_in[4];
  const float* odd_vector   = (const float*)d_in[5];
  const float* even_vector  = (const float*)d_in[6];
  const float* even_tensor  = (const float*)d_in[7];
  const float* odd_tensor   = (const float*)d_in[8];
  const float* W            = (const float*)d_in[9];
  const float* b            = (const float*)d_in[10];
  float* out = (float*)d_out;

  const size_t adBytes = (size_t)AN * ASTRIDE * sizeof(float);
  float* ad = (float*)d_ws;
  float* P  = (float*)((char*)d_ws + adBytes);

  int nsplit = 32;
  while (nsplit > 1 &&
         adBytes + (size_t)nsplit * NFIELDS * QN * sizeof(float) > ws_size)
    nsplit >>= 1;
  const int chunk = AN / nsplit;

  precompute_atoms<<<AN / 4, 256, 0, stream>>>(
      atom_coords, alpha, even_scalar, odd_scalar, odd_vector, even_vector,
      even_tensor, odd_tensor, W, b, ad);
  splat_partial<<<dim3(QN / 256, nsplit), 256, 0, stream>>>(
      query_coords, ad, b, P, chunk);
  finalize<<<QN / 256, 256, 0, stream>>>(P, out, nsplit);
}

// Round 2
// 65.764 us; speedup vs baseline: 1.1624x; 1.1624x over previous
//
#include <hip/hip_runtime.h>
#include <math.h>

#define QN 8192
#define AN 2048
#define DN 64
#define ASTRIDE 40
#define NFIELDS 17

#define SQ2f      1.4142135623730951f
#define INV_SQ2f  0.7071067811865476f
#define SQ6_INVf  0.4082482904638631f
#define SQ2_3f    0.816496580927726f

__device__ __forceinline__ float wave_sum(float v) {
#pragma unroll
  for (int off = 32; off > 0; off >>= 1) v += __shfl_xor(v, off, 64);
  return v;
}

// ---------------- Kernel A: per-atom precompute ----------------
// out[a][0..39]:
//  0-2 coords, 3 alpha, 4 c0e, 5 c0o, 6-8 dip(+b), 9-11 biv(+b),
//  12-17 quad sym [xx,xy,xz,yy,yz,zz], 18-23 odd quad sym,
//  24-26 a1o, 27-29 a1e, 30-34 a2e, 35-39 a2o
__global__ __launch_bounds__(256) void precompute_atoms(
    const float* __restrict__ atom_coords, const float* __restrict__ alpha,
    const float* __restrict__ even_scalar, const float* __restrict__ odd_scalar,
    const float* __restrict__ odd_vector, const float* __restrict__ even_vector,
    const float* __restrict__ even_tensor, const float* __restrict__ odd_tensor,
    const float* __restrict__ W, const float* __restrict__ b,
    float* __restrict__ out)
{
  const int a = blockIdx.x * 4 + (threadIdx.x >> 6);
  const int d = threadIdx.x & 63;

  const float es  = even_scalar[a * DN + d];
  const float os  = odd_scalar[a * DN + d];
  const float ov0 = odd_vector[(a * DN + d) * 3 + 0];
  const float ov1 = odd_vector[(a * DN + d) * 3 + 1];
  const float ov2 = odd_vector[(a * DN + d) * 3 + 2];
  const float ev0 = even_vector[(a * DN + d) * 3 + 0];
  const float ev1 = even_vector[(a * DN + d) * 3 + 1];
  const float ev2 = even_vector[(a * DN + d) * 3 + 2];
  const float et0 = even_tensor[(a * DN + d) * 5 + 0];
  const float et1 = even_tensor[(a * DN + d) * 5 + 1];
  const float et2 = even_tensor[(a * DN + d) * 5 + 2];
  const float et3 = even_tensor[(a * DN + d) * 5 + 3];
  const float et4 = even_tensor[(a * DN + d) * 5 + 4];
  const float ot0 = odd_tensor[(a * DN + d) * 5 + 0];
  const float ot1 = odd_tensor[(a * DN + d) * 5 + 1];
  const float ot2 = odd_tensor[(a * DN + d) * 5 + 2];
  const float ot3 = odd_tensor[(a * DN + d) * 5 + 3];
  const float ot4 = odd_tensor[(a * DN + d) * 5 + 4];

  const float w0 = W[0 * DN + d];
  const float w1 = W[1 * DN + d];
  const float w2 = W[2 * DN + d];
  const float w3 = W[3 * DN + d];
  const float w4 = W[4 * DN + d];
  const float w5 = W[5 * DN + d];
  const float w6 = W[6 * DN + d];
  const float w7 = W[7 * DN + d];
  const float w8 = W[8 * DN + d];
  const float w9 = W[9 * DN + d];

  float r[34];
  r[0]  = es * w0;
  r[1]  = os * w1;
  r[2]  = ov0 * w2; r[3]  = ov1 * w2; r[4]  = ov2 * w2;
  r[5]  = ev0 * w3; r[6]  = ev1 * w3; r[7]  = ev2 * w3;
  r[8]  = et0 * w4; r[9]  = et1 * w4; r[10] = et2 * w4; r[11] = et3 * w4; r[12] = et4 * w4;
  r[13] = ot0 * w5; r[14] = ot1 * w5; r[15] = ot2 * w5; r[16] = ot3 * w5; r[17] = ot4 * w5;
  r[18] = ov0 * w6; r[19] = ov1 * w6; r[20] = ov2 * w6;
  r[21] = ev0 * w7; r[22] = ev1 * w7; r[23] = ev2 * w7;
  r[24] = et0 * w8; r[25] = et1 * w8; r[26] = et2 * w8; r[27] = et3 * w8; r[28] = et4 * w8;
  r[29] = ot0 * w9; r[30] = ot1 * w9; r[31] = ot2 * w9; r[32] = ot3 * w9; r[33] = ot4 * w9;

#pragma unroll
  for (int k = 0; k < 34; ++k) r[k] = wave_sum(r[k]);

  if (d == 0) {
    float* o = out + (size_t)a * ASTRIDE;
    o[0] = atom_coords[a * 3 + 0];
    o[1] = atom_coords[a * 3 + 1];
    o[2] = atom_coords[a * 3 + 2];
    o[3] = alpha[a];
    o[4] = r[0] + b[0];
    o[5] = r[1] + b[1];
    o[6] = r[2] + b[2]; o[7] = r[3] + b[2]; o[8] = r[4] + b[2];
    o[9] = r[5] + b[3]; o[10] = r[6] + b[3]; o[11] = r[7] + b[3];
    {
      float c0 = r[8] + b[4], c1 = r[9] + b[4], c2 = r[10] + b[4],
            c3 = r[11] + b[4], c4 = r[12] + b[4];
      float zz = c1 * SQ2_3f;
      float xx = 0.5f * (c0 * SQ2f - zz);
      float yy = 0.5f * (-c0 * SQ2f - zz);
      float xy = c2 * INV_SQ2f, xz = c3 * INV_SQ2f, yz = c4 * INV_SQ2f;
      o[12] = xx; o[13] = xy; o[14] = xz; o[15] = yy; o[16] = yz; o[17] = zz;
    }
    {
      float c0 = r[13] + b[5], c1 = r[14] + b[5], c2 = r[15] + b[5],
            c3 = r[16] + b[5], c4 = r[17] + b[5];
      float zz = c1 * SQ2_3f;
      float xx = 0.5f * (c0 * SQ2f - zz);
      float yy = 0.5f * (-c0 * SQ2f - zz);
      float xy = c2 * INV_SQ2f, xz = c3 * INV_SQ2f, yz = c4 * INV_SQ2f;
      o[18] = xx; o[19] = xy; o[20] = xz; o[21] = yy; o[22] = yz; o[23] = zz;
    }
    o[24] = r[18]; o[25] = r[19]; o[26] = r[20];
    o[27] = r[21]; o[28] = r[22]; o[29] = r[23];
    o[30] = r[24]; o[31] = r[25]; o[32] = r[26]; o[33] = r[27]; o[34] = r[28];
    o[35] = r[29]; o[36] = r[30]; o[37] = r[31]; o[38] = r[32]; o[39] = r[33];
  }
}

// ---------------- Kernel B: pair loop, software-pipelined float4 loads --------
// P layout: P[(s*NFIELDS + f)*QN + q]
__global__ __launch_bounds__(256, 4) void splat_partial(
    const float* __restrict__ qcoord, const float* __restrict__ ad,
    const float* __restrict__ b, float* __restrict__ P, int chunk)
{
  const int q = blockIdx.x * 256 + threadIdx.x;
  const int s = blockIdx.y;

  const float qx = qcoord[q * 3 + 0];
  const float qy = qcoord[q * 3 + 1];
  const float qz = qcoord[q * 3 + 2];
  const float b_ea = b[6] + b[8];
  const float b_oa = b[7] + b[9];

  float Sw = 0.f, Sc0e = 0.f, Sc0o = 0.f;
  float Sdx = 0.f, Sdy = 0.f, Sdz = 0.f;
  float Sqx = 0.f, Sqy = 0.f, Sqz = 0.f;
  float Sbx = 0.f, Sby = 0.f, Sbz = 0.f;
  float Sox = 0.f, Soy = 0.f, Soz = 0.f;
  float Sea = 0.f, Soa = 0.f;

  const float* base = ad + (size_t)(s * chunk) * ASTRIDE;

  auto body = [&](const float4 (&c)[10]) {
    const float ax = c[0].x, ay = c[0].y, az = c[0].z, al = c[0].w;
    const float dx = qx - ax, dy = qy - ay, dz = qz - az;
    const float d2 = fmaf(dx, dx, fmaf(dy, dy, dz * dz));
    const float w = __expf(-al * d2);
    const float inv = (d2 > 1e-12f) ? __builtin_amdgcn_rsqf(d2) : 0.0f;
    const float ux = dx * inv, uy = dy * inv, uz = dz * inv;
    const float xx = ux * ux, yy = uy * uy, zz = uz * uz;
    const float y0 = (xx - yy) * INV_SQ2f;
    const float y1 = (2.0f * zz - xx - yy) * SQ6_INVf;
    const float y2 = SQ2f * ux * uy;
    const float y3 = SQ2f * ux * uz;
    const float y4 = SQ2f * uy * uz;

    Sw += w;
    Sc0e = fmaf(w, c[1].x, Sc0e);
    Sc0o = fmaf(w, c[1].y, Sc0o);
    Sdx = fmaf(w, c[1].z, Sdx); Sdy = fmaf(w, c[1].w, Sdy); Sdz = fmaf(w, c[2].x, Sdz);
    Sbx = fmaf(w, c[2].y, Sbx); Sby = fmaf(w, c[2].z, Sby); Sbz = fmaf(w, c[2].w, Sbz);

    const float wux = w * ux, wuy = w * uy, wuz = w * uz;
    Sqx = fmaf(c[3].x, wux, fmaf(c[3].y, wuy, fmaf(c[3].z, wuz, Sqx)));
    Sqy = fmaf(c[3].y, wux, fmaf(c[3].w, wuy, fmaf(c[4].x, wuz, Sqy)));
    Sqz = fmaf(c[3].z, wux, fmaf(c[4].x, wuy, fmaf(c[4].y, wuz, Sqz)));
    Sox = fmaf(c[4].z, wux, fmaf(c[4].w, wuy, fmaf(c[5].x, wuz, Sox)));
    Soy = fmaf(c[4].w, wux, fmaf(c[5].y, wuy, fmaf(c[5].z, wuz, Soy)));
    Soz = fmaf(c[5].x, wux, fmaf(c[5].z, wuy, fmaf(c[5].w, wuz, Soz)));

    const float e_ang = fmaf(ux, c[6].x, fmaf(uy, c[6].y, fmaf(uz, c[6].z,
                        fmaf(y0, c[7].z, fmaf(y1, c[7].w, fmaf(y2, c[8].x,
                        fmaf(y3, c[8].y, fmaf(y4, c[8].z, b_ea))))))));
    const float o_ang = fmaf(ux, c[6].w, fmaf(uy, c[7].x, fmaf(uz, c[7].y,
                        fmaf(y0, c[8].w, fmaf(y1, c[9].x, fmaf(y2, c[9].y,
                        fmaf(y3, c[9].z, fmaf(y4, c[9].w, b_oa))))))));
    Sea = fmaf(w, e_ang, Sea);
    Soa = fmaf(w, o_ang, Soa);
  };

  float4 cA[10], cB[10];
  {
    const float4* p = (const float4*)base;
#pragma unroll
    for (int k = 0; k < 10; ++k) cA[k] = p[k];
  }
  int i = 0;
  // chunk is always even (>= 64); 2-deep pipeline with alternating banks
  for (; i + 2 < chunk; i += 2) {
    {
      const float4* p = (const float4*)(base + (size_t)(i + 1) * ASTRIDE);
#pragma unroll
      for (int k = 0; k < 10; ++k) cB[k] = p[k];
    }
    body(cA);
    {
      const float4* p = (const float4*)(base + (size_t)(i + 2) * ASTRIDE);
#pragma unroll
      for (int k = 0; k < 10; ++k) cA[k] = p[k];
    }
    body(cB);
  }
  {
    const float4* p = (const float4*)(base + (size_t)(i + 1) * ASTRIDE);
#pragma unroll
    for (int k = 0; k < 10; ++k) cB[k] = p[k];
  }
  body(cA);
  body(cB);

  float* Pb = P + (size_t)s * NFIELDS * QN + q;
  Pb[0 * QN]  = Sw;
  Pb[1 * QN]  = Sc0e;
  Pb[2 * QN]  = Sc0o;
  Pb[3 * QN]  = Sdx;  Pb[4 * QN]  = Sdy;  Pb[5 * QN]  = Sdz;
  Pb[6 * QN]  = Sqx;  Pb[7 * QN]  = Sqy;  Pb[8 * QN]  = Sqz;
  Pb[9 * QN]  = Sbx;  Pb[10 * QN] = Sby;  Pb[11 * QN] = Sbz;
  Pb[12 * QN] = Sox;  Pb[13 * QN] = Soy;  Pb[14 * QN] = Soz;
  Pb[15 * QN] = Sea;
  Pb[16 * QN] = Soa;
}

// ---------------- Kernel C1: reduce split partials, one field per block.y ----
__global__ __launch_bounds__(256) void reduce_splits(
    const float* __restrict__ P, float* __restrict__ F, int nsplit)
{
  const int q = blockIdx.x * 256 + threadIdx.x;
  const int f = blockIdx.y;
  float acc = 0.f;
  for (int s = 0; s < nsplit; ++s)
    acc += P[((size_t)s * NFIELDS + f) * QN + q];
  F[(size_t)f * QN + q] = acc;
}

// ---------------- Kernel C2: finalize outputs from F[17][QN] ----------------
__global__ __launch_bounds__(256) void combine(
    const float* __restrict__ F, float* __restrict__ out)
{
  const int q = blockIdx.x * 256 + threadIdx.x;
  float acc[NFIELDS];
#pragma unroll
  for (int f = 0; f < NFIELDS; ++f) acc[f] = F[(size_t)f * QN + q];

  const float Sw = fmaxf(acc[0], 1e-8f);
  const float inv = 1.0f / Sw;
  const float scal = acc[1] * inv;
  const float pse  = acc[2] * inv;
  const float vx = (acc[3] + acc[6]) * inv;
  const float vy = (acc[4] + acc[7]) * inv;
  const float vz = (acc[5] + acc[8]) * inv;
  const float bx = (acc[9] + acc[12]) * inv;
  const float by = (acc[10] + acc[13]) * inv;
  const float bz = (acc[11] + acc[14]) * inv;
  const float ea = acc[15] * inv;
  const float oa = acc[16] * inv;

  const float evenc = scal + ea;
  const float oddc  = pse + oa;
  const float vn = sqrtf(fmaf(vx, vx, fmaf(vy, vy, vz * vz)));
  const float bn = sqrtf(fmaf(bx, bx, fmaf(by, by, bz * bz)));
  const float total = evenc + oddc + 0.1f * vn + 0.05f * bn;

  out[q] = total;
  out[QN + q] = evenc;
  out[2 * QN + q] = oddc;
  float* mv = out + 3 * QN + (size_t)q * 16;
  mv[0] = scal;
  mv[1] = vx; mv[2] = vy; mv[3] = vz;
  mv[4] = 0.f;
  mv[5] = bz; mv[6] = -by; mv[7] = bx;
  mv[8] = 0.f; mv[9] = 0.f; mv[10] = 0.f;
  mv[11] = pse;
  mv[12] = 0.f; mv[13] = 0.f; mv[14] = 0.f; mv[15] = 0.f;
}

extern "C" void kernel_launch(void* const* d_in, const int* in_sizes, int n_in,
                              void* d_out, int out_size, void* d_ws, size_t ws_size,
                              hipStream_t stream) {
  const float* query_coords = (const float*)d_in[0];
  const float* atom_coords  = (const float*)d_in[1];
  const float* alpha        = (const float*)d_in[2];
  const float* even_scalar  = (const float*)d_in[3];
  const float* odd_scalar   = (const float*)d_in[4];
  const float* odd_vector   = (const float*)d_in[5];
  const float* even_vector  = (const float*)d_in[6];
  const float* even_tensor  = (const float*)d_in[7];
  const float* odd_tensor   = (const float*)d_in[8];
  const float* W            = (const float*)d_in[9];
  const float* b            = (const float*)d_in[10];
  float* out = (float*)d_out;

  const size_t adBytes = (size_t)AN * ASTRIDE * sizeof(float);
  const size_t fBytes  = (size_t)NFIELDS * QN * sizeof(float);
  float* ad = (float*)d_ws;
  float* F  = (float*)((char*)d_ws + adBytes);
  float* P  = (float*)((char*)d_ws + adBytes + fBytes);

  int nsplit = 32;
  while (nsplit > 1 &&
         adBytes + fBytes + (size_t)nsplit * NFIELDS * QN * sizeof(float) > ws_size)
    nsplit >>= 1;
  const int chunk = AN / nsplit;

  precompute_atoms<<<AN / 4, 256, 0, stream>>>(
      atom_coords, alpha, even_scalar, odd_scalar, odd_vector, even_vector,
      even_tensor, odd_tensor, W, b, ad);
  splat_partial<<<dim3(QN / 256, nsplit), 256, 0, stream>>>(
      query_coords, ad, b, P, chunk);
  reduce_splits<<<dim3(QN / 256, NFIELDS), 256, 0, stream>>>(P, F, nsplit);
  combine<<<QN / 256, 256, 0, stream>>>(F, out);
}

// Round 3
// 65.317 us; speedup vs baseline: 1.1703x; 1.0068x over previous
//
#include <hip/hip_runtime.h>
#include <math.h>

#define QN 8192
#define AN 2048
#define DN 64
#define AS2 44          // floats per atom record (11 float4)
#define NFIELDS 11

#define SQ2f      1.4142135623730951f
#define INV_SQ2f  0.7071067811865476f
#define SQ6_INVf  0.4082482904638631f
#define LOG2Ef    1.4426950408889634f

__device__ __forceinline__ float wave_sum(float v) {
#pragma unroll
  for (int off = 32; off > 0; off >>= 1) v += __shfl_xor(v, off, 64);
  return v;
}

// ---------------- Kernel A: per-atom precompute ----------------
// record[a][0..43] (11 float4):
//  v0: ax, ay, az, -alpha*log2e
//  v1: c0e(+b0), c0o(+b1), dipx(+b2), dipy
//  v2: dipz, bivx(+b3), bivy, bivz
//  v3: Qxx,Qxy,Qxz,Qyy   v4: Qyz,Qzz,Oxx,Oxy   v5: Oxz,Oyy,Oyz,Ozz
//  v6: le_x,le_y,le_z,lo_x   v7: lo_y,lo_z,qe_xx,qe_yy   v8: qe_zz,qe_xy,qe_xz,qe_yz
//  v9: qo_xx,qo_yy,qo_zz,qo_xy   v10: qo_xz,qo_yz,0,0
__global__ __launch_bounds__(256) void precompute_atoms(
    const float* __restrict__ atom_coords, const float* __restrict__ alpha,
    const float* __restrict__ even_scalar, const float* __restrict__ odd_scalar,
    const float* __restrict__ odd_vector, const float* __restrict__ even_vector,
    const float* __restrict__ even_tensor, const float* __restrict__ odd_tensor,
    const float* __restrict__ W, const float* __restrict__ b,
    float* __restrict__ out)
{
  const int a = blockIdx.x * 4 + (threadIdx.x >> 6);
  const int d = threadIdx.x & 63;

  const float es  = even_scalar[a * DN + d];
  const float os  = odd_scalar[a * DN + d];
  const float ov0 = odd_vector[(a * DN + d) * 3 + 0];
  const float ov1 = odd_vector[(a * DN + d) * 3 + 1];
  const float ov2 = odd_vector[(a * DN + d) * 3 + 2];
  const float ev0 = even_vector[(a * DN + d) * 3 + 0];
  const float ev1 = even_vector[(a * DN + d) * 3 + 1];
  const float ev2 = even_vector[(a * DN + d) * 3 + 2];
  const float et0 = even_tensor[(a * DN + d) * 5 + 0];
  const float et1 = even_tensor[(a * DN + d) * 5 + 1];
  const float et2 = even_tensor[(a * DN + d) * 5 + 2];
  const float et3 = even_tensor[(a * DN + d) * 5 + 3];
  const float et4 = even_tensor[(a * DN + d) * 5 + 4];
  const float ot0 = odd_tensor[(a * DN + d) * 5 + 0];
  const float ot1 = odd_tensor[(a * DN + d) * 5 + 1];
  const float ot2 = odd_tensor[(a * DN + d) * 5 + 2];
  const float ot3 = odd_tensor[(a * DN + d) * 5 + 3];
  const float ot4 = odd_tensor[(a * DN + d) * 5 + 4];

  const float w0 = W[0 * DN + d];
  const float w1 = W[1 * DN + d];
  const float w2 = W[2 * DN + d];
  const float w3 = W[3 * DN + d];
  const float w4 = W[4 * DN + d];
  const float w5 = W[5 * DN + d];
  const float w6 = W[6 * DN + d];
  const float w7 = W[7 * DN + d];
  const float w8 = W[8 * DN + d];
  const float w9 = W[9 * DN + d];

  float r[34];
  r[0]  = es * w0;
  r[1]  = os * w1;
  r[2]  = ov0 * w2; r[3]  = ov1 * w2; r[4]  = ov2 * w2;
  r[5]  = ev0 * w3; r[6]  = ev1 * w3; r[7]  = ev2 * w3;
  r[8]  = et0 * w4; r[9]  = et1 * w4; r[10] = et2 * w4; r[11] = et3 * w4; r[12] = et4 * w4;
  r[13] = ot0 * w5; r[14] = ot1 * w5; r[15] = ot2 * w5; r[16] = ot3 * w5; r[17] = ot4 * w5;
  r[18] = ov0 * w6; r[19] = ov1 * w6; r[20] = ov2 * w6;
  r[21] = ev0 * w7; r[22] = ev1 * w7; r[23] = ev2 * w7;
  r[24] = et0 * w8; r[25] = et1 * w8; r[26] = et2 * w8; r[27] = et3 * w8; r[28] = et4 * w8;
  r[29] = ot0 * w9; r[30] = ot1 * w9; r[31] = ot2 * w9; r[32] = ot3 * w9; r[33] = ot4 * w9;

#pragma unroll
  for (int k = 0; k < 34; ++k) r[k] = wave_sum(r[k]);

  if (d == 0) {
    float* o = out + (size_t)a * AS2;
    o[0] = atom_coords[a * 3 + 0];
    o[1] = atom_coords[a * 3 + 1];
    o[2] = atom_coords[a * 3 + 2];
    o[3] = -alpha[a] * LOG2Ef;
    o[4] = r[0] + b[0];
    o[5] = r[1] + b[1];
    o[6] = r[2] + b[2]; o[7] = r[3] + b[2]; o[8] = r[4] + b[2];
    o[9] = r[5] + b[3]; o[10] = r[6] + b[3]; o[11] = r[7] + b[3];
    {
      float c0 = r[8] + b[4], c1 = r[9] + b[4], c2 = r[10] + b[4],
            c3 = r[11] + b[4], c4 = r[12] + b[4];
      float zz = c1 * 0.816496580927726f;
      float xx = 0.5f * (c0 * SQ2f - zz);
      float yy = 0.5f * (-c0 * SQ2f - zz);
      float xy = c2 * INV_SQ2f, xz = c3 * INV_SQ2f, yz = c4 * INV_SQ2f;
      o[12] = xx; o[13] = xy; o[14] = xz; o[15] = yy; o[16] = yz; o[17] = zz;
    }
    {
      float c0 = r[13] + b[5], c1 = r[14] + b[5], c2 = r[15] + b[5],
            c3 = r[16] + b[5], c4 = r[17] + b[5];
      float zz = c1 * 0.816496580927726f;
      float xx = 0.5f * (c0 * SQ2f - zz);
      float yy = 0.5f * (-c0 * SQ2f - zz);
      float xy = c2 * INV_SQ2f, xz = c3 * INV_SQ2f, yz = c4 * INV_SQ2f;
      o[18] = xx; o[19] = xy; o[20] = xz; o[21] = yy; o[22] = yz; o[23] = zz;
    }
    o[24] = r[18]; o[25] = r[19]; o[26] = r[20];     // le
    o[27] = r[21]; o[28] = r[22]; o[29] = r[23];     // lo
    {
      float A0 = r[24] * INV_SQ2f, A1 = r[25] * SQ6_INVf;
      float A2 = r[26] * SQ2f, A3 = r[27] * SQ2f, A4 = r[28] * SQ2f;
      o[30] = A0 - A1; o[31] = -A0 - A1; o[32] = 2.0f * A1;
      o[33] = A2; o[34] = A3; o[35] = A4;
    }
    {
      float A0 = r[29] * INV_SQ2f, A1 = r[30] * SQ6_INVf;
      float A2 = r[31] * SQ2f, A3 = r[32] * SQ2f, A4 = r[33] * SQ2f;
      o[36] = A0 - A1; o[37] = -A0 - A1; o[38] = 2.0f * A1;
      o[39] = A2; o[40] = A3; o[41] = A4;
    }
    o[42] = 0.f; o[43] = 0.f;
  }
}

// ---------------- Kernel B: pair loop, LDS-staged atom records ----------------
// P layout: P[(s*NFIELDS + f)*QN + q]
__global__ __launch_bounds__(256, 8) void splat_partial(
    const float* __restrict__ qcoord, const float* __restrict__ ad,
    float* __restrict__ P, int chunk)
{
  extern __shared__ float4 sm[];   // chunk * 11 float4
  const int tid = threadIdx.x;
  const int q = blockIdx.x * 256 + tid;
  const int s = blockIdx.y;

  // stage this block's atom chunk into LDS (coalesced)
  {
    const float4* src = (const float4*)(ad + (size_t)(s * chunk) * AS2);
    const int n4 = chunk * 11;
    for (int t = tid; t < n4; t += 256) sm[t] = src[t];
  }

  const float qx = qcoord[q * 3 + 0];
  const float qy = qcoord[q * 3 + 1];
  const float qz = qcoord[q * 3 + 2];
  __syncthreads();

  float Sw = 0.f, Se = 0.f, So = 0.f;
  float Svx = 0.f, Svy = 0.f, Svz = 0.f;
  float Sbx = 0.f, Sby = 0.f, Sbz = 0.f;
  float Sea = 0.f, Soa = 0.f;

  for (int i = 0; i < chunk; ++i) {
    const float4* c = sm + i * 11;
    const float4 c0 = c[0];
    const float dx = qx - c0.x, dy = qy - c0.y, dz = qz - c0.z;
    const float d2 = fmaf(dx, dx, fmaf(dy, dy, dz * dz));
    const float w = __builtin_amdgcn_exp2f(c0.w * d2);   // c0.w = -alpha*log2e
    const float inv = __builtin_amdgcn_rsqf(d2);
    const float inv2 = inv * inv;
    const float g1 = w * inv, g2 = w * inv2;

    const float4 c1 = c[1], c2 = c[2];
    Sw += w;
    Se = fmaf(w, c1.x, Se); So = fmaf(w, c1.y, So);
    Svx = fmaf(w, c1.z, Svx); Svy = fmaf(w, c1.w, Svy); Svz = fmaf(w, c2.x, Svz);
    Sbx = fmaf(w, c2.y, Sbx); Sby = fmaf(w, c2.z, Sby); Sbz = fmaf(w, c2.w, Sbz);

    const float wdx = g1 * dx, wdy = g1 * dy, wdz = g1 * dz;
    const float4 c3 = c[3], c4 = c[4], c5 = c[5];
    Svx = fmaf(c3.x, wdx, fmaf(c3.y, wdy, fmaf(c3.z, wdz, Svx)));
    Svy = fmaf(c3.y, wdx, fmaf(c3.w, wdy, fmaf(c4.x, wdz, Svy)));
    Svz = fmaf(c3.z, wdx, fmaf(c4.x, wdy, fmaf(c4.y, wdz, Svz)));
    Sbx = fmaf(c4.z, wdx, fmaf(c4.w, wdy, fmaf(c5.x, wdz, Sbx)));
    Sby = fmaf(c4.w, wdx, fmaf(c5.y, wdy, fmaf(c5.z, wdz, Sby)));
    Sbz = fmaf(c5.x, wdx, fmaf(c5.z, wdy, fmaf(c5.w, wdz, Sbz)));

    const float xx = dx * dx, yy = dy * dy, zz = dz * dz;
    const float xy = dx * dy, xz = dx * dz, yz = dy * dz;
    const float4 c6 = c[6], c7 = c[7], c8 = c[8], c9 = c[9], c10 = c[10];
    const float lin_e = fmaf(dx, c6.x, fmaf(dy, c6.y, dz * c6.z));
    const float qd_e  = fmaf(xx, c7.z, fmaf(yy, c7.w, fmaf(zz, c8.x,
                        fmaf(xy, c8.y, fmaf(xz, c8.z, yz * c8.w)))));
    Sea = fmaf(g1, lin_e, fmaf(g2, qd_e, Sea));
    const float lin_o = fmaf(dx, c6.w, fmaf(dy, c7.x, dz * c7.y));
    const float qd_o  = fmaf(xx, c9.x, fmaf(yy, c9.y, fmaf(zz, c9.z,
                        fmaf(xy, c9.w, fmaf(xz, c10.x, yz * c10.y)))));
    Soa = fmaf(g1, lin_o, fmaf(g2, qd_o, Soa));
  }

  float* Pb = P + (size_t)s * NFIELDS * QN + q;
  Pb[0 * QN]  = Sw;
  Pb[1 * QN]  = Se;
  Pb[2 * QN]  = So;
  Pb[3 * QN]  = Svx;  Pb[4 * QN]  = Svy;  Pb[5 * QN]  = Svz;
  Pb[6 * QN]  = Sbx;  Pb[7 * QN]  = Sby;  Pb[8 * QN]  = Sbz;
  Pb[9 * QN]  = Sea;
  Pb[10 * QN] = Soa;
}

// ---------------- Kernel C1: reduce split partials, one field per block.y ----
__global__ __launch_bounds__(256) void reduce_splits(
    const float* __restrict__ P, float* __restrict__ F, int nsplit)
{
  const int q = blockIdx.x * 256 + threadIdx.x;
  const int f = blockIdx.y;
  float acc = 0.f;
  for (int s = 0; s < nsplit; ++s)
    acc += P[((size_t)s * NFIELDS + f) * QN + q];
  F[(size_t)f * QN + q] = acc;
}

// ---------------- Kernel C2: finalize outputs from F[11][QN] ----------------
__global__ __launch_bounds__(256) void combine(
    const float* __restrict__ F, const float* __restrict__ b,
    float* __restrict__ out)
{
  const int q = blockIdx.x * 256 + threadIdx.x;
  float acc[NFIELDS];
#pragma unroll
  for (int f = 0; f < NFIELDS; ++f) acc[f] = F[(size_t)f * QN + q];

  const float b_ea = b[6] + b[8];
  const float b_oa = b[7] + b[9];

  const float Sw = fmaxf(acc[0], 1e-8f);
  const float inv = 1.0f / Sw;
  const float snw = acc[0] * inv;             // == 1 unless clamped
  const float scal = acc[1] * inv;
  const float pse  = acc[2] * inv;
  const float vx = acc[3] * inv;
  const float vy = acc[4] * inv;
  const float vz = acc[5] * inv;
  const float bx = acc[6] * inv;
  const float by = acc[7] * inv;
  const float bz = acc[8] * inv;
  const float ea = fmaf(b_ea, snw, acc[9] * inv);
  const float oa = fmaf(b_oa, snw, acc[10] * inv);

  const float evenc = scal + ea;
  const float oddc  = pse + oa;
  const float vn = sqrtf(fmaf(vx, vx, fmaf(vy, vy, vz * vz)));
  const float bn = sqrtf(fmaf(bx, bx, fmaf(by, by, bz * bz)));
  const float total = evenc + oddc + 0.1f * vn + 0.05f * bn;

  out[q] = total;
  out[QN + q] = evenc;
  out[2 * QN + q] = oddc;
  float* mv = out + 3 * QN + (size_t)q * 16;
  mv[0] = scal;
  mv[1] = vx; mv[2] = vy; mv[3] = vz;
  mv[4] = 0.f;
  mv[5] = bz; mv[6] = -by; mv[7] = bx;
  mv[8] = 0.f; mv[9] = 0.f; mv[10] = 0.f;
  mv[11] = pse;
  mv[12] = 0.f; mv[13] = 0.f; mv[14] = 0.f; mv[15] = 0.f;
}

extern "C" void kernel_launch(void* const* d_in, const int* in_sizes, int n_in,
                              void* d_out, int out_size, void* d_ws, size_t ws_size,
                              hipStream_t stream) {
  const float* query_coords = (const float*)d_in[0];
  const float* atom_coords  = (const float*)d_in[1];
  const float* alpha        = (const float*)d_in[2];
  const float* even_scalar  = (const float*)d_in[3];
  const float* odd_scalar   = (const float*)d_in[4];
  const float* odd_vector   = (const float*)d_in[5];
  const float* even_vector  = (const float*)d_in[6];
  const float* even_tensor  = (const float*)d_in[7];
  const float* odd_tensor   = (const float*)d_in[8];
  const float* W            = (const float*)d_in[9];
  const float* b            = (const float*)d_in[10];
  float* out = (float*)d_out;

  const size_t adBytes = (size_t)AN * AS2 * sizeof(float);
  const size_t fBytes  = (size_t)NFIELDS * QN * sizeof(float);
  float* ad = (float*)d_ws;
  float* F  = (float*)((char*)d_ws + adBytes);
  float* P  = (float*)((char*)d_ws + adBytes + fBytes);

  int nsplit = 64;
  while (nsplit > 1 &&
         adBytes + fBytes + (size_t)nsplit * NFIELDS * QN * sizeof(float) > ws_size)
    nsplit >>= 1;
  const int chunk = AN / nsplit;
  const size_t smBytes = (size_t)chunk * 11 * sizeof(float4);

  precompute_atoms<<<AN / 4, 256, 0, stream>>>(
      atom_coords, alpha, even_scalar, odd_scalar, odd_vector, even_vector,
      even_tensor, odd_tensor, W, b, ad);
  splat_partial<<<dim3(QN / 256, nsplit), 256, smBytes, stream>>>(
      query_coords, ad, P, chunk);
  reduce_splits<<<dim3(QN / 256, NFIELDS), 256, 0, stream>>>(P, F, nsplit);
  combine<<<QN / 256, 256, 0, stream>>>(F, b, out);
}